// Round 1
// baseline (188.888 us; speedup 1.0000x reference)
//
#include <hip/hip_runtime.h>
#include <math.h>

#define TLEN 8192
#define NTH  512
#define EPT  16          // elements per thread

__device__ __forceinline__ float max3f(float a, float b, float c) {
    float r;
    asm("v_max3_f32 %0, %1, %2, %3" : "=v"(r) : "v"(a), "v"(b), "v"(c));
    return r;
}
__device__ __forceinline__ float min3f(float a, float b, float c) {
    float r;
    asm("v_min3_f32 %0, %1, %2, %3" : "=v"(r) : "v"(a), "v"(b), "v"(c));
    return r;
}

__global__ __launch_bounds__(NTH, 6) void hurst_kernel(const float* __restrict__ x,
                                                       float* __restrict__ out) {
    // 32 KB swizzled row staging (conflict-free b128 transpose)
    __shared__ float4 stage[2048];
    __shared__ float wsum[8], wssq[8];     // per-wave scan totals
    __shared__ float Sp[33], SSp[33];      // exclusive prefix at 256-elem boundaries
    __shared__ float meanL[62], SL[62];    // per-chunk mean / clamped std (all scales)
    __shared__ float p3max[8], p3min[8];   // scale-3 per-wave partials (chunks span 2 waves)
    __shared__ float p4max[8], p4min[8];   // scale-4 per-wave partials (chunks span 4 waves)
    __shared__ float rsb[62];              // per-chunk R/S

    const int t = threadIdx.x;
    const int lane = t & 63;
    const int wave = t >> 6;
    const float4* xq = reinterpret_cast<const float4*>(x + (long long)blockIdx.x * TLEN);

    // ---- coalesced global load, swizzled transpose-store to LDS ----
    // global float4 g is owned by thread o=g>>2 slot j=g&3, stored at p=4o+(j^((o>>1)&3))
    #pragma unroll
    for (int jj = 0; jj < 4; ++jj) {
        const int g = t + NTH * jj;                 // lane-contiguous: 8 segs/instr
        const float4 f = xq[g];
        const int o = g >> 2;
        const int j = g & 3;
        const int p = (o << 2) + (j ^ ((o >> 1) & 3));
        stage[p] = f;
    }
    __syncthreads();                                 // B0

    // ---- each thread pulls its 16 contiguous elements (conflict-free b128) ----
    float4 v[4];
    #pragma unroll
    for (int j = 0; j < 4; ++j) {
        const int p = (t << 2) + (j ^ ((t >> 1) & 3));
        v[j] = stage[p];
    }

    // ---- local inclusive prefix (L) + sum + sumsq, in registers ----
    float L[EPT];
    float run = 0.f, ssq = 0.f;
    #pragma unroll
    for (int j = 0; j < 4; ++j) {
        float a0 = v[j].x, a1 = v[j].y, a2 = v[j].z, a3 = v[j].w;
        run += a0; L[4*j+0] = run; ssq = fmaf(a0, a0, ssq);
        run += a1; L[4*j+1] = run; ssq = fmaf(a1, a1, ssq);
        run += a2; L[4*j+2] = run; ssq = fmaf(a2, a2, ssq);
        run += a3; L[4*j+3] = run; ssq = fmaf(a3, a3, ssq);
    }
    const float ssum = run;

    // ---- wave-inclusive scan of (sum, sumsq) across 64 lanes ----
    float v1 = ssum, v2 = ssq;
    #pragma unroll
    for (int d = 1; d < 64; d <<= 1) {
        float u1 = __shfl_up(v1, d, 64);
        float u2 = __shfl_up(v2, d, 64);
        if (lane >= d) { v1 += u1; v2 += u2; }
    }
    if (lane == 63) { wsum[wave] = v1; wssq[wave] = v2; }
    __syncthreads();                                 // B1

    float woff1 = 0.f, woff2 = 0.f;
    #pragma unroll
    for (int w = 0; w < 7; ++w) {
        if (wave > w) { woff1 += wsum[w]; woff2 += wssq[w]; }
    }
    const float ex1 = woff1 + (v1 - ssum);   // sum of elems [0, 16t)
    const float ex2 = woff2 + (v2 - ssq);    // sumsq of elems [0, 16t)

    // 256-elem-boundary prefixes (boundary every 16 threads)
    if ((t & 15) == 0) { Sp[t >> 4] = ex1; SSp[t >> 4] = ex2; }
    if (t == NTH - 1)  { Sp[32] = ex1 + ssum; SSp[32] = ex2 + ssq; }

    // global inclusive prefix, register-resident
    #pragma unroll
    for (int k = 0; k < EPT; ++k) L[k] += ex1;
    __syncthreads();                                 // B2

    // ---- all 62 chunk (mean, std) in one shot ----
    if (t < 62) {
        int si, ci;
        if (t < 32)      { si = 0; ci = t; }
        else if (t < 48) { si = 1; ci = t - 32; }
        else if (t < 56) { si = 2; ci = t - 48; }
        else if (t < 60) { si = 3; ci = t - 56; }
        else             { si = 4; ci = t - 60; }
        int a = ci << si, b = (ci + 1) << si;
        float s_f = (float)(256 << si);
        float sum = Sp[b] - Sp[a];
        float sq  = SSp[b] - SSp[a];
        float m = sum / s_f;
        float var = (sq - s_f * m * m) / (s_f - 1.0f);
        meanL[t] = m;
        SL[t] = fmaxf(sqrtf(fmaxf(var, 0.f)), 1e-8f);
    }
    __syncthreads();                                 // B3

    // ---- per-scale max/min of h = P[i] - (i_rel+1)*m ----
    #pragma unroll
    for (int si = 0; si < 5; ++si) {
        const int lg = 4 + si;
        const int g = 16 << si;                // threads per chunk: 16..256
        const int OFF = (si == 0) ? 0 : (si == 1) ? 32 : (si == 2) ? 48
                      : (si == 3) ? 56 : 60;
        const int c = t >> lg;                 // chunk id within scale
        const float m = meanL[OFF + c];
        const int rel = t & (g - 1);           // thread pos within chunk
        const float m2 = m + m;
        float accA = (float)(EPT * rel + 1) * m;   // (local k=0 pos + 1)*m
        float accB = accA + m;
        float hmax = -INFINITY, hmin = INFINITY;
        #pragma unroll
        for (int u = 0; u < EPT / 2; ++u) {
            float h0 = L[2*u]   - accA;
            float h1 = L[2*u+1] - accB;
            accA += m2;
            accB += m2;
            hmax = max3f(hmax, h0, h1);
            hmin = min3f(hmin, h0, h1);
        }
        const int bw = (g < 64) ? g : 64;
        #pragma unroll
        for (int w = 1; w < bw; w <<= 1) {
            hmax = fmaxf(hmax, __shfl_xor(hmax, w, 64));
            hmin = fminf(hmin, __shfl_xor(hmin, w, 64));
        }
        if (si < 3) {
            if (rel == 0) {
                float R = hmax - hmin;
                rsb[OFF + c] = fmaxf(R / SL[OFF + c], 1e-8f);
            }
        } else if (si == 3) {
            if (lane == 0) { p3max[wave] = hmax; p3min[wave] = hmin; }
        } else {
            if (lane == 0) { p4max[wave] = hmax; p4min[wave] = hmin; }
        }
    }
    __syncthreads();                                 // B4

    if (t < 4) {   // scale-3 chunks: merge 2 wave partials each
        float mx = fmaxf(p3max[2*t], p3max[2*t+1]);
        float mn = fminf(p3min[2*t], p3min[2*t+1]);
        rsb[56 + t] = fmaxf((mx - mn) / SL[56 + t], 1e-8f);
    }
    if (t >= 4 && t < 6) {   // scale-4 chunks: merge 4 wave partials each
        int c = t - 4;
        float mx = fmaxf(fmaxf(p4max[4*c], p4max[4*c+1]),
                         fmaxf(p4max[4*c+2], p4max[4*c+3]));
        float mn = fminf(fminf(p4min[4*c], p4min[4*c+1]),
                         fminf(p4min[4*c+2], p4min[4*c+3]));
        rsb[60 + c] = fmaxf((mx - mn) / SL[60 + c], 1e-8f);
    }
    __syncthreads();                                 // B5

    float lrv = 0.f;
    if (t < 5) {
        const int nc  = 32 >> t;
        const int OFF = (t == 0) ? 0 : (t == 1) ? 32 : (t == 2) ? 48
                      : (t == 3) ? 56 : 60;
        float s = 0.f;
        for (int j = 0; j < nc; ++j) s += rsb[OFF + j];
        lrv = logf(fmaxf(s / (float)nc, 1e-8f));
    }
    if (wave == 0) {
        float n0 = __shfl(lrv, 0, 64);
        float n1 = __shfl(lrv, 1, 64);
        float n3 = __shfl(lrv, 3, 64);
        float n4 = __shfl(lrv, 4, 64);
        if (lane == 0) {
            // centered ln(s) = (si-2)*ln2; H = num/(10*ln2^2), one ln2 cancels
            float H = (-2.f * n0 - n1 + n3 + 2.f * n4)
                      * (1.0f / (10.0f * 0.69314718055994530942f));
            H = fminf(fmaxf(H, 0.05f), 0.95f);
            out[blockIdx.x] = H;
        }
    }
}

extern "C" void kernel_launch(void* const* d_in, const int* in_sizes, int n_in,
                              void* d_out, int out_size, void* d_ws, size_t ws_size,
                              hipStream_t stream) {
    const float* x = (const float*)d_in[0];
    float* out = (float*)d_out;
    const int B = in_sizes[0] / TLEN;          // 4096 rows
    hurst_kernel<<<dim3(B), dim3(NTH), 0, stream>>>(x, out);
}

// Round 3
// 186.517 us; speedup vs baseline: 1.0127x; 1.0127x over previous
//
#include <hip/hip_runtime.h>
#include <math.h>

#define TLEN 8192
#define NTH  512
#define EPT  16          // elements per thread

static __device__ __forceinline__ float max3f(float a, float b, float c) {
    float r;
    asm("v_max3_f32 %0, %1, %2, %3" : "=v"(r) : "v"(a), "v"(b), "v"(c));
    return r;
}
static __device__ __forceinline__ float min3f(float a, float b, float c) {
    float r;
    asm("v_min3_f32 %0, %1, %2, %3" : "=v"(r) : "v"(a), "v"(b), "v"(c));
    return r;
}

__global__ __launch_bounds__(NTH, 6) void hurst_kernel(const float* __restrict__ x,
                                                       float* __restrict__ out) {
    // 32 KB swizzled row staging (conflict-free b128 transpose)
    __shared__ float4 stage[2048];
    __shared__ float wsum[8], wssq[8];     // per-wave scan totals
    __shared__ float Sp[33], SSp[33];      // exclusive prefix at 256-elem boundaries
    __shared__ float meanL[62], SL[62];    // per-chunk mean / clamped std (all scales)
    __shared__ float p3max[8], p3min[8];   // scale-3 per-wave partials
    __shared__ float p4max[8], p4min[8];   // scale-4 per-wave partials
    __shared__ float rsb[62];              // per-chunk R/S

    const int t = threadIdx.x;
    const int lane = t & 63;
    const int wave = t >> 6;
    const float4* xq = reinterpret_cast<const float4*>(x + (long long)blockIdx.x * TLEN);

    // ---- coalesced global load, swizzled transpose-store to LDS ----
    #pragma unroll
    for (int jj = 0; jj < 4; ++jj) {
        const int g = t + NTH * jj;                 // lane-contiguous
        const float4 f = xq[g];
        const int o = g >> 2;
        const int j = g & 3;
        stage[(o << 2) + (j ^ ((o >> 1) & 3))] = f;
    }
    __syncthreads();                                 // B0

    // ---- pull 16 contiguous elems (conflict-free b128), fuse into prefix ----
    float L[EPT];                                    // LOCAL inclusive prefix
    float run = 0.f, ssq = 0.f;
    #pragma unroll
    for (int j = 0; j < 4; ++j) {
        const float4 f = stage[(t << 2) + (j ^ ((t >> 1) & 3))];
        run += f.x; L[4*j+0] = run; ssq = fmaf(f.x, f.x, ssq);
        run += f.y; L[4*j+1] = run; ssq = fmaf(f.y, f.y, ssq);
        run += f.z; L[4*j+2] = run; ssq = fmaf(f.z, f.z, ssq);
        run += f.w; L[4*j+3] = run; ssq = fmaf(f.w, f.w, ssq);
    }
    const float ssum = run;

    // ---- wave-inclusive scan of (sum, sumsq) across 64 lanes ----
    float v1 = ssum, v2 = ssq;
    #pragma unroll
    for (int d = 1; d < 64; d <<= 1) {
        float u1 = __shfl_up(v1, d, 64);
        float u2 = __shfl_up(v2, d, 64);
        if (lane >= d) { v1 += u1; v2 += u2; }
    }
    if (lane == 63) { wsum[wave] = v1; wssq[wave] = v2; }
    __syncthreads();                                 // B1

    float woff1 = 0.f, woff2 = 0.f;
    #pragma unroll
    for (int w = 0; w < 7; ++w) {
        if (wave > w) { woff1 += wsum[w]; woff2 += wssq[w]; }
    }
    const float ex1 = woff1 + (v1 - ssum);   // sum of elems [0, 16t)
    const float ex2 = woff2 + (v2 - ssq);    // sumsq of elems [0, 16t)

    // 256-elem-boundary prefixes (boundary every 16 threads)
    if ((t & 15) == 0) { Sp[t >> 4] = ex1; SSp[t >> 4] = ex2; }
    if (t == NTH - 1)  { Sp[32] = ex1 + ssum; SSp[32] = ex2 + ssq; }
    __syncthreads();                                 // B2

    // ---- all 62 chunk (mean, std) in one shot ----
    if (t < 62) {
        int si, ci;
        if (t < 32)      { si = 0; ci = t; }
        else if (t < 48) { si = 1; ci = t - 32; }
        else if (t < 56) { si = 2; ci = t - 48; }
        else if (t < 60) { si = 3; ci = t - 56; }
        else             { si = 4; ci = t - 60; }
        int a = ci << si, b = (ci + 1) << si;
        float s_f = (float)(256 << si);
        float sum = Sp[b] - Sp[a];
        float sq  = SSp[b] - SSp[a];
        float m = sum / s_f;
        float var = (sq - s_f * m * m) / (s_f - 1.0f);
        meanL[t] = m;
        SL[t] = fmaxf(sqrtf(fmaxf(var, 0.f)), 1e-8f);
    }
    __syncthreads();                                 // B3

    const float tb = (float)(t << 4);      // 16t, exact in fp32

    // ---- per-scale R = max-min of (P[i] - i*m); per-thread offset
    //      (ex1 - 16t*m) is constant over the 16 local elems -> apply ONCE ----
    #pragma unroll
    for (int si = 0; si < 5; ++si) {
        const int lg = 4 + si;
        const int g = 16 << si;                // threads per chunk: 16..256
        const int OFF = (si == 0) ? 0 : (si == 1) ? 32 : (si == 2) ? 48
                      : (si == 3) ? 56 : 60;
        const int c = t >> lg;                 // chunk id within scale
        const float m = meanL[OFF + c];
        const int rel = t & (g - 1);
        float hmax = -INFINITY, hmin = INFINITY;
        #pragma unroll
        for (int u = 0; u < EPT; u += 2) {
            const float h0 = fmaf(-m, (float)u,       L[u]);
            const float h1 = fmaf(-m, (float)(u + 1), L[u + 1]);
            hmax = max3f(hmax, h0, h1);
            hmin = min3f(hmin, h0, h1);
        }
        const float cst = fmaf(-m, tb, ex1);   // per-thread, per-scale constant
        hmax += cst;
        hmin += cst;
        const int bw = (g < 64) ? g : 64;
        #pragma unroll
        for (int w = 1; w < bw; w <<= 1) {
            hmax = fmaxf(hmax, __shfl_xor(hmax, w, 64));
            hmin = fminf(hmin, __shfl_xor(hmin, w, 64));
        }
        if (si < 3) {
            if (rel == 0) {
                float R = hmax - hmin;
                rsb[OFF + c] = fmaxf(R / SL[OFF + c], 1e-8f);
            }
        } else if (si == 3) {
            if (lane == 0) { p3max[wave] = hmax; p3min[wave] = hmin; }
        } else {
            if (lane == 0) { p4max[wave] = hmax; p4min[wave] = hmin; }
        }
    }
    __syncthreads();                                 // B4

    if (t < 4) {   // scale-3 chunks: merge 2 wave partials each
        float mx = fmaxf(p3max[2*t], p3max[2*t+1]);
        float mn = fminf(p3min[2*t], p3min[2*t+1]);
        rsb[56 + t] = fmaxf((mx - mn) / SL[56 + t], 1e-8f);
    }
    if (t >= 4 && t < 6) {   // scale-4 chunks: merge 4 wave partials each
        int c = t - 4;
        float mx = fmaxf(fmaxf(p4max[4*c], p4max[4*c+1]),
                         fmaxf(p4max[4*c+2], p4max[4*c+3]));
        float mn = fminf(fminf(p4min[4*c], p4min[4*c+1]),
                         fminf(p4min[4*c+2], p4min[4*c+3]));
        rsb[60 + c] = fmaxf((mx - mn) / SL[60 + c], 1e-8f);
    }
    __syncthreads();                                 // B5

    float lrv = 0.f;
    if (t < 5) {
        const int nc  = 32 >> t;
        const int OFF = (t == 0) ? 0 : (t == 1) ? 32 : (t == 2) ? 48
                      : (t == 3) ? 56 : 60;
        float s = 0.f;
        for (int j = 0; j < nc; ++j) s += rsb[OFF + j];
        lrv = logf(fmaxf(s / (float)nc, 1e-8f));
    }
    if (wave == 0) {
        float n0 = __shfl(lrv, 0, 64);
        float n1 = __shfl(lrv, 1, 64);
        float n3 = __shfl(lrv, 3, 64);
        float n4 = __shfl(lrv, 4, 64);
        if (lane == 0) {
            // centered ln(s) = (si-2)*ln2; H = num/(10*ln2^2), one ln2 cancels
            float H = (-2.f * n0 - n1 + n3 + 2.f * n4)
                      * (1.0f / (10.0f * 0.69314718055994530942f));
            H = fminf(fmaxf(H, 0.05f), 0.95f);
            out[blockIdx.x] = H;
        }
    }
}

extern "C" void kernel_launch(void* const* d_in, const int* in_sizes, int n_in,
                              void* d_out, int out_size, void* d_ws, size_t ws_size,
                              hipStream_t stream) {
    const float* x = (const float*)d_in[0];
    float* out = (float*)d_out;
    const int B = in_sizes[0] / TLEN;          // 4096 rows
    hurst_kernel<<<dim3(B), dim3(NTH), 0, stream>>>(x, out);
}